// Round 11
// baseline (209.832 us; speedup 1.0000x reference)
//
#include <hip/hip_runtime.h>

#define BSZ 2
#define SEQ 2048
#define CH  1024
#define NH  16
#define HD  64
#define LOG2E 1.4426950408889634f
#define MASKC (-14426.950408889634f)   /* -10000 * log2(e) */

typedef short  bf16x8 __attribute__((ext_vector_type(8)));
typedef short  bf16x4 __attribute__((ext_vector_type(4)));
typedef float  f32x4  __attribute__((ext_vector_type(4)));

__device__ __forceinline__ short f2bf(float f) {
    union { float f; unsigned u; } v; v.f = f;
    unsigned r = v.u + 0x7FFFu + ((v.u >> 16) & 1u);   // RNE
    return (short)(r >> 16);
}
// round-half-up bf16 (1 ulp tie-only difference vs RNE, 2 VALU ops)
__device__ __forceinline__ short f2bf_fast(float f) {
    union { float f; unsigned u; } v; v.f = f;
    return (short)((v.u + 0x8000u) >> 16);
}
// Single-instruction exp2 THROUGH THE COMPILER (TRANS-op result hazard needs
// a compiler-inserted wait state; bare inline asm broke correctness in R6).
__device__ __forceinline__ float exp2_hw(float x) {
#if __has_builtin(__builtin_amdgcn_exp2f)
    return __builtin_amdgcn_exp2f(x);
#else
    float r;
    asm volatile("v_exp_f32 %0, %1\n\ts_nop 1" : "=v"(r) : "v"(x));
    return r;
#endif
}

// 16x16x16 bf16 MFMA (K=16): C/D layout of a 16x16 MFMA equals this op's
// B-operand layout, which is what makes register-resident P^T possible.
#if __has_builtin(__builtin_amdgcn_mfma_f32_16x16x16bf16_1k)
__device__ __forceinline__ f32x4 mfma16x16x16(bf16x4 a, bf16x4 b, f32x4 c) {
    return __builtin_amdgcn_mfma_f32_16x16x16bf16_1k(a, b, c, 0, 0, 0);
}
#else
__device__ __forceinline__ f32x4 mfma16x16x16(bf16x4 a, bf16x4 b, f32x4 c) {
    f32x4 d;
    asm("v_mfma_f32_16x16x16_bf16 %0, %1, %2, %3"
        : "=v"(d) : "v"(a), "v"(b), "v"(c));
    return d;
}
#endif

// ---------------------------------------------------------------------------
// PREP mega-kernel (R9 structure + mask): one launch, block-range dispatch.
//   [0, 2048)     : query fp32 -> qc bf16
//   [2048, 4096)  : key   fp32 -> kc bf16
//   [4096, 4608)  : Wq/Wk [k][n] -> wtq/wtk [n][k] bf16
//   [4608, 5632)  : key [b][s][h*64+d] -> vtr [b*h][d][s] bf16
//   [5632, 5648)  : amask int -> mf float addend (*log2e)
// ---------------------------------------------------------------------------
__global__ __launch_bounds__(256) void prep(
    const float* __restrict__ query, const float* __restrict__ key,
    const float* __restrict__ Wq, const float* __restrict__ Wk,
    const int*   __restrict__ am,
    short* __restrict__ qc, short* __restrict__ kc,
    short* __restrict__ wtq, short* __restrict__ wtk,
    short* __restrict__ vtr, float* __restrict__ mf)
{
    __shared__ float tile[64][65];
    const int bid = blockIdx.x;
    const int tid = threadIdx.x;

    if (bid < 4096) {
        const float* s = (bid < 2048) ? query : key;
        short*       d = (bid < 2048) ? qc : kc;
        long i = ((long)(bid & 2047) * 256 + tid) * 8;
        float4 v0 = *(const float4*)&s[i];
        float4 v1 = *(const float4*)&s[i + 4];
        bf16x8 o;
        o[0] = f2bf(v0.x); o[1] = f2bf(v0.y); o[2] = f2bf(v0.z); o[3] = f2bf(v0.w);
        o[4] = f2bf(v1.x); o[5] = f2bf(v1.y); o[6] = f2bf(v1.z); o[7] = f2bf(v1.w);
        *(bf16x8*)&d[i] = o;
        return;
    }
    if (bid >= 5632) {
        int i = (bid - 5632) * 256 + tid;
        mf[i] = (1.0f - (float)am[i]) * MASKC;
        return;
    }

    // ---- 64x64 tiled transpose + cast ----
    const float* s; short* d;
    int r0, c0, srs, drs;
    if (bid < 4608) {
        int t = bid - 4096;           // 0..511
        s   = (t < 256) ? Wq : Wk;
        d   = (t < 256) ? wtq : wtk;
        t  &= 255;
        r0  = (t >> 4) * 64;          // k
        c0  = (t & 15) * 64;          // n
        srs = CH; drs = CH;
    } else {
        int t = bid - 4608;           // 0..1023
        int z = t >> 5;               // b*16+h, 0..31
        int sy = t & 31;              // s tile, 0..31
        s   = key + (long)(z >> 4) * SEQ * CH + (long)(z & 15) * HD;
        d   = vtr + (long)z * HD * SEQ;
        r0  = sy * 64;                // s
        c0  = 0;                      // d
        srs = CH; drs = SEQ;
    }

    const int r  = tid >> 2;          // 0..63
    const int c4 = (tid & 3) << 4;    // 0,16,32,48
    #pragma unroll
    for (int i = 0; i < 16; i += 4) {
        float4 v = *(const float4*)&s[(long)(r0 + r) * srs + c0 + c4 + i];
        tile[r][c4 + i + 0] = v.x;
        tile[r][c4 + i + 1] = v.y;
        tile[r][c4 + i + 2] = v.z;
        tile[r][c4 + i + 3] = v.w;
    }
    __syncthreads();
    bf16x8 o0, o1;
    #pragma unroll
    for (int i = 0; i < 8; i++) o0[i] = f2bf(tile[c4 + i][r]);
    #pragma unroll
    for (int i = 0; i < 8; i++) o1[i] = f2bf(tile[c4 + 8 + i][r]);
    *(bf16x8*)&d[(long)(c0 + r) * drs + r0 + c4 + 0] = o0;
    *(bf16x8*)&d[(long)(c0 + r) * drs + r0 + c4 + 8] = o1;
}

// ---------------------------------------------------------------------------
// Fused Q+K projection GEMM (blockIdx.z selects operand set), all-bf16 inputs
// (R9 version — the R10 fp32-staging variant cost ~18 µs).  128x128 tile,
// BK=64 (16 iters), 4 waves of 4x4 16x16x32 MFMAs x 2 k-halves.  Double-
// buffered LDS, ONE barrier per iter.
// ---------------------------------------------------------------------------
__global__ __launch_bounds__(256, 2) void proj_mfma(
    const short* __restrict__ Xq, const short* __restrict__ Xk,
    const short* __restrict__ Wtq, const short* __restrict__ Wtk,
    const float* __restrict__ bq_, const float* __restrict__ bk_,
    short* __restrict__ Yq, short* __restrict__ Yk)
{
    __shared__ short At[2][128 * 72];
    __shared__ short Bt[2][128 * 72];
    const int zz = blockIdx.z;
    const short* X    = zz ? Xk  : Xq;
    const short* Wt   = zz ? Wtk : Wtq;
    const float* bias = zz ? bk_ : bq_;
    short*       Y    = zz ? Yk  : Yq;
    const float scale = zz ? 1.0f : (0.125f * LOG2E);  // fold 1/sqrt(D)*log2e into Q

    const int tid  = threadIdx.x;
    const int lane = tid & 63, w = tid >> 6;
    const int quad = lane >> 4, t16 = lane & 15;
    const int m0 = blockIdx.y * 128, n0 = blockIdx.x * 128;
    const int srow = tid >> 1;            // 0..127 staging row
    const int shalf = (tid & 1) * 32;     // 0 / 32 k-half (shorts)

    f32x4 acc[4][4];
    #pragma unroll
    for (int i = 0; i < 4; i++)
        #pragma unroll
        for (int j = 0; j < 4; j++)
            acc[i][j] = (f32x4){0.f, 0.f, 0.f, 0.f};

    const int M0 = (w >> 1) * 64, N0 = (w & 1) * 64;
    const int NIT = CH / 64;

    bf16x8 ar[4], br[4];
    #pragma unroll
    for (int c = 0; c < 4; c++) {
        ar[c] = *(const bf16x8*)&X [(long)(m0 + srow) * CH + shalf + 8 * c];
        br[c] = *(const bf16x8*)&Wt[(long)(n0 + srow) * CH + shalf + 8 * c];
    }
    #pragma unroll
    for (int c = 0; c < 4; c++) {
        *(bf16x8*)&At[0][srow * 72 + shalf + 8 * c] = ar[c];
        *(bf16x8*)&Bt[0][srow * 72 + shalf + 8 * c] = br[c];
    }
    #pragma unroll
    for (int c = 0; c < 4; c++) {
        ar[c] = *(const bf16x8*)&X [(long)(m0 + srow) * CH + 64 + shalf + 8 * c];
        br[c] = *(const bf16x8*)&Wt[(long)(n0 + srow) * CH + 64 + shalf + 8 * c];
    }
    __syncthreads();

    for (int it = 0; it < NIT; it++) {
        const int buf = it & 1;
        if (it + 1 < NIT) {
            #pragma unroll
            for (int c = 0; c < 4; c++) {
                *(bf16x8*)&At[buf ^ 1][srow * 72 + shalf + 8 * c] = ar[c];
                *(bf16x8*)&Bt[buf ^ 1][srow * 72 + shalf + 8 * c] = br[c];
            }
            if (it + 2 < NIT) {
                const long ko = (long)(it + 2) * 64;
                #pragma unroll
                for (int c = 0; c < 4; c++) {
                    ar[c] = *(const bf16x8*)&X [(long)(m0 + srow) * CH + ko + shalf + 8 * c];
                    br[c] = *(const bf16x8*)&Wt[(long)(n0 + srow) * CH + ko + shalf + 8 * c];
                }
            }
        }

        #pragma unroll
        for (int kk = 0; kk < 2; kk++) {
            bf16x8 af[4], bw[4];
            #pragma unroll
            for (int im = 0; im < 4; im++)
                af[im] = *(bf16x8*)&At[buf][(M0 + 16 * im + t16) * 72 + kk * 32 + quad * 8];
            #pragma unroll
            for (int jn = 0; jn < 4; jn++)
                bw[jn] = *(bf16x8*)&Bt[buf][(N0 + 16 * jn + t16) * 72 + kk * 32 + quad * 8];
            #pragma unroll
            for (int im = 0; im < 4; im++)
                #pragma unroll
                for (int jn = 0; jn < 4; jn++)
                    acc[im][jn] = __builtin_amdgcn_mfma_f32_16x16x32_bf16(
                        af[im], bw[jn], acc[im][jn], 0, 0, 0);
        }
        __syncthreads();
    }

    #pragma unroll
    for (int jn = 0; jn < 4; jn++) {
        float bs = bias[n0 + N0 + 16 * jn + t16];
        #pragma unroll
        for (int im = 0; im < 4; im++)
            #pragma unroll
            for (int reg = 0; reg < 4; reg++) {
                float y = (acc[im][jn][reg] + bs) * scale;
                Y[(long)(m0 + M0 + 16 * im + 4 * quad + reg) * (NH * HD)
                  + n0 + N0 + 16 * jn + t16] = f2bf(y);
            }
    }
}

// ---------------------------------------------------------------------------
// Flash attention, TRANSPOSED-SCORE form, register-resident P, SPLIT-K.
// blockIdx.z = b*nkh + kh; each block handles SEQ/nkh keys.  Fixed-max
// softmax makes the split merge trivial: out = sum_kh(O)/sum_kh(l) — no
// max bookkeeping.  nkh=2 -> grid 1024 = 4 blocks/CU (16 waves/CU) vs the
// grid-limited 2/CU at nkh=1.  Partials: O raw fp32 + l per q-row.
// Everything else identical to the proven R7/R10 loop.
// ---------------------------------------------------------------------------
__global__ __launch_bounds__(256, 4) void attn_mfma(
    const short* __restrict__ qp,    // [B*S][1024] bf16, pre-scaled 0.125*log2e
    const short* __restrict__ kp,    // [B*S][1024] bf16
    const short* __restrict__ vt,    // [B*H][64][S] bf16 (V transposed)
    const float* __restrict__ mf,    // [B][S] mask addend * log2e
    float* __restrict__ out,         // [B][S][H][D] fp32 (nkh==1 path)
    float* __restrict__ opA,         // partial O, kh=0
    float* __restrict__ opB,         // partial O, kh=1
    float* __restrict__ lp,          // partial l [kh][(b*S+q)*NH+h]
    int nkh)
{
    __shared__ short Kt[2][64 * 72];    // [key][d]
    __shared__ short Vt[2][64 * 72];    // [d][key]

    const int qt0 = blockIdx.x * 128;
    const int h   = blockIdx.y;
    const int b   = blockIdx.z / nkh;
    const int kh  = blockIdx.z - b * nkh;
    const int tid = threadIdx.x;
    const int lane = tid & 63, w = tid >> 6;
    const int quad = lane >> 4, t16 = lane & 15;
    const int NIT = (SEQ / 64) / nkh;
    const int khbase = kh * (SEQ / nkh);

    // Q B-frags, loaded once: B[k = ds*32+quad*8+j][q = qm*16+t16]
    bf16x8 qf[2][2];
    #pragma unroll
    for (int qm = 0; qm < 2; qm++)
        #pragma unroll
        for (int ds = 0; ds < 2; ds++)
            qf[qm][ds] = *(const bf16x8*)&qp[
                (long)(b * SEQ + qt0 + w * 32 + qm * 16 + t16) * CH
                + h * HD + ds * 32 + quad * 8];

    f32x4 oa[4][2];                  // [dt][qm]: out^T [d=16dt+4quad+reg][q]
    float l_r[2];
    #pragma unroll
    for (int dt = 0; dt < 4; dt++)
        #pragma unroll
        for (int qm = 0; qm < 2; qm++)
            oa[dt][qm] = (f32x4){0.f, 0.f, 0.f, 0.f};
    l_r[0] = l_r[1] = 0.f;

    const int srow  = tid >> 2;           // 0..63
    const int scol  = (tid & 3) * 16;     // 0,16,32,48
    const long kbase = (long)(b * SEQ) * CH + h * HD;
    const long vbase = ((long)(b * NH + h) * HD) * SEQ;

    bf16x8 kr[2], vr[2];
    // tile 0 -> regs -> buf0; tile 1 -> regs
    #pragma unroll
    for (int c = 0; c < 2; c++) {
        kr[c] = *(const bf16x8*)&kp[kbase + (long)(khbase + srow) * CH + scol + 8 * c];
        vr[c] = *(const bf16x8*)&vt[vbase + (long)srow * SEQ + khbase + scol + 8 * c];
    }
    #pragma unroll
    for (int c = 0; c < 2; c++) {
        *(bf16x8*)&Kt[0][srow * 72 + scol + 8 * c] = kr[c];
        *(bf16x8*)&Vt[0][srow * 72 + scol + 8 * c] = vr[c];
    }
    #pragma unroll
    for (int c = 0; c < 2; c++) {
        kr[c] = *(const bf16x8*)&kp[kbase + (long)(khbase + 64 + srow) * CH + scol + 8 * c];
        vr[c] = *(const bf16x8*)&vt[vbase + (long)srow * SEQ + khbase + 64 + scol + 8 * c];
    }
    __syncthreads();

    for (int it = 0; it < NIT; it++) {
        const int buf = it & 1;
        const int kt0 = khbase + it * 64;

        if (it + 1 < NIT) {
            #pragma unroll
            for (int c = 0; c < 2; c++) {
                *(bf16x8*)&Kt[buf ^ 1][srow * 72 + scol + 8 * c] = kr[c];
                *(bf16x8*)&Vt[buf ^ 1][srow * 72 + scol + 8 * c] = vr[c];
            }
            if (it + 2 < NIT) {
                const int kn = kt0 + 128;
                #pragma unroll
                for (int c = 0; c < 2; c++) {
                    kr[c] = *(const bf16x8*)&kp[kbase + (long)(kn + srow) * CH + scol + 8 * c];
                    vr[c] = *(const bf16x8*)&vt[vbase + (long)srow * SEQ + kn + scol + 8 * c];
                }
            }
        }

        // mask addend, per key row: regs 0..3 <- keys kt0+16jt+4quad+0..3
        float4 mv4[4];
        #pragma unroll
        for (int jt = 0; jt < 4; jt++)
            mv4[jt] = *(const float4*)&mf[b * SEQ + kt0 + jt * 16 + quad * 4];

        // ---- S^T = K * Q^T  (mask pre-loaded into the accumulator) ----
        f32x4 sa[2][4];
        #pragma unroll
        for (int qm = 0; qm < 2; qm++)
            #pragma unroll
            for (int jt = 0; jt < 4; jt++)
                sa[qm][jt] = (f32x4){mv4[jt].x, mv4[jt].y, mv4[jt].z, mv4[jt].w};
        #pragma unroll
        for (int ds = 0; ds < 2; ds++) {
            bf16x8 kb[4];   // A[m=key t16][k=d]
            #pragma unroll
            for (int jt = 0; jt < 4; jt++)
                kb[jt] = *(bf16x8*)&Kt[buf][(jt * 16 + t16) * 72 + ds * 32 + quad * 8];
            #pragma unroll
            for (int qm = 0; qm < 2; qm++)
                #pragma unroll
                for (int jt = 0; jt < 4; jt++)
                    sa[qm][jt] = __builtin_amdgcn_mfma_f32_16x16x32_bf16(
                        kb[jt], qf[qm][ds], sa[qm][jt], 0, 0, 0);
        }

        // ---- fixed-max softmax + pack to PV B-frags (own registers!) ----
        bf16x4 pb[2][4];
        #pragma unroll
        for (int qm = 0; qm < 2; qm++)
            #pragma unroll
            for (int jt = 0; jt < 4; jt++) {
                float p0 = exp2_hw(sa[qm][jt][0]);
                float p1 = exp2_hw(sa[qm][jt][1]);
                float p2 = exp2_hw(sa[qm][jt][2]);
                float p3 = exp2_hw(sa[qm][jt][3]);
                l_r[qm] += (p0 + p1) + (p2 + p3);
                bf16x4 pk;
                pk[0] = f2bf_fast(p0); pk[1] = f2bf_fast(p1);
                pk[2] = f2bf_fast(p2); pk[3] = f2bf_fast(p3);
                pb[qm][jt] = pk;
            }

        // ---- out^T += V^T * P^T  (16x16x16, A from LDS b64, B = pb regs) ----
        #pragma unroll
        for (int jt = 0; jt < 4; jt++) {
            bf16x4 va[4];   // A[m=d t16][k=key 4quad+j]
            #pragma unroll
            for (int dt = 0; dt < 4; dt++)
                va[dt] = *(bf16x4*)&Vt[buf][(dt * 16 + t16) * 72 + jt * 16 + quad * 4];
            #pragma unroll
            for (int dt = 0; dt < 4; dt++)
                #pragma unroll
                for (int qm = 0; qm < 2; qm++)
                    oa[dt][qm] = mfma16x16x16(va[dt], pb[qm][jt], oa[dt][qm]);
        }
        __syncthreads();
    }

    // ---- epilogue: quad-reduce l; direct store (nkh=1) or partials ----
    #pragma unroll
    for (int qm = 0; qm < 2; qm++) {
        float l = l_r[qm];
        l += __shfl_xor(l, 16, 64);
        l += __shfl_xor(l, 32, 64);
        int q = qt0 + w * 32 + qm * 16 + t16;
        long row = (long)(b * SEQ + q) * NH + h;
        if (nkh == 1) {
            float inv = 1.0f / l;
            #pragma unroll
            for (int dt = 0; dt < 4; dt++) {
                f32x4 o = oa[dt][qm];
                float4 st = {o[0] * inv, o[1] * inv, o[2] * inv, o[3] * inv};
                *(float4*)&out[row * HD + dt * 16 + quad * 4] = st;
            }
        } else {
            float* op = kh ? opB : opA;
            if (quad == 0) lp[(long)kh * (BSZ * SEQ * NH) + row] = l;
            #pragma unroll
            for (int dt = 0; dt < 4; dt++) {
                f32x4 o = oa[dt][qm];
                float4 st = {o[0], o[1], o[2], o[3]};
                *(float4*)&op[row * HD + dt * 16 + quad * 4] = st;
            }
        }
    }
}

// ---------------------------------------------------------------------------
// Split-K merge: out = (O0 + O1) / (l0 + l1).  4M floats, float4/thread.
// ---------------------------------------------------------------------------
__global__ __launch_bounds__(256) void reduce_split(
    const float* __restrict__ o0, const float* __restrict__ o1,
    const float* __restrict__ lp, float* __restrict__ out)
{
    long i4 = (long)blockIdx.x * 256 + threadIdx.x;   // float4 index
    long e  = i4 * 4;
    long row = i4 >> 4;                               // 64 floats per row
    float4 a = *(const float4*)&o0[e];
    float4 b = *(const float4*)&o1[e];
    float inv = 1.0f / (lp[row] + lp[(long)(BSZ * SEQ * NH) + row]);
    float4 o = {(a.x + b.x) * inv, (a.y + b.y) * inv,
                (a.z + b.z) * inv, (a.w + b.w) * inv};
    *(float4*)&out[e] = o;
}

extern "C" void kernel_launch(void* const* d_in, const int* in_sizes, int n_in,
                              void* d_out, int out_size, void* d_ws, size_t ws_size,
                              hipStream_t stream) {
    const float* query = (const float*)d_in[0];
    const float* key   = (const float*)d_in[1];
    const int*   amask = (const int*)d_in[2];
    const float* Wq    = (const float*)d_in[3];
    const float* bq    = (const float*)d_in[4];
    const float* Wk    = (const float*)d_in[5];
    const float* bk    = (const float*)d_in[6];
    float* out = (float*)d_out;

    char* ws = (char*)d_ws;
    const long MB = 1024 * 1024;
    short* qc  = (short*)(ws + 0 * MB);    // query bf16 (8 MB) — dead after proj
    short* kc  = (short*)(ws + 8 * MB);    // key   bf16 (8 MB) — dead after proj
    short* qp  = (short*)(ws + 16 * MB);   // Q proj bf16 (8 MB)
    short* kp  = (short*)(ws + 24 * MB);   // K proj bf16 (8 MB)
    short* vtr = (short*)(ws + 32 * MB);   // V^T bf16 (8 MB)
    short* wtq = (short*)(ws + 40 * MB);   // Wq^T bf16 (2 MB)
    short* wtk = (short*)(ws + 42 * MB);   // Wk^T bf16 (2 MB)
    float* mfv = (float*)(ws + 44 * MB);   // mask addend [4096] f32 (16 KB)
    // split-K extras (only if ws is big enough):
    float* opA = (float*)(ws + 0 * MB);    // partial O kh=0 (16 MB, reuses qc+kc)
    float* opB = (float*)(ws + 45 * MB);   // partial O kh=1 (16 MB)
    float* lpp = (float*)(ws + 61 * MB);   // partial l [2][65536] (512 KB)

    const bool split = ws_size >= (size_t)(62 * MB);
    const int  nkh   = split ? 2 : 1;

    prep<<<dim3(5648), 256, 0, stream>>>(query, key, Wq, Wk, amask,
                                         qc, kc, wtq, wtk, vtr, mfv);

    dim3 pgrid((NH * HD) / 128, (BSZ * SEQ) / 128, 2);   // 8 x 32 x 2 = 512
    proj_mfma<<<pgrid, 256, 0, stream>>>(qc, kc, wtq, wtk, bq, bk, qp, kp);

    dim3 agrid(SEQ / 128, NH, BSZ * nkh);                 // 16 x 16 x {2,4}
    attn_mfma<<<agrid, 256, 0, stream>>>(qp, kp, vtr, mfv, out,
                                         opA, opB, lpp, nkh);

    if (split) {
        // 4M floats / 4 per thread / 256 threads = 4096 blocks
        reduce_split<<<dim3(4096), 256, 0, stream>>>(opA, opB, lpp, out);
    }
}